// Round 1
// baseline (85.967 us; speedup 1.0000x reference)
//
#include <hip/hip_runtime.h>
#include <hip/hip_bf16.h>

// Local (trunked) attention, MI355X gfx950.
// B=1, H=16, N=16384, d=64 fp32; trunks of 32 queries x 128-key window,
// pad_left=48, no 1/sqrt(d) scaling. One wave per trunk.

typedef _Float16 f16x8 __attribute__((ext_vector_type(8)));
typedef float f32x4 __attribute__((ext_vector_type(4)));

#define NSEQ   16384
#define DHEAD  64
#define NQ     32
#define NKEYS  128
#define PADL   48
#define TPH    512      // trunks per head

__device__ __forceinline__ f16x8 cvt8(const float* __restrict__ p) {
  const float4 a = *reinterpret_cast<const float4*>(p);
  const float4 b = *reinterpret_cast<const float4*>(p + 4);
  f16x8 r;
  r[0] = (_Float16)a.x; r[1] = (_Float16)a.y;
  r[2] = (_Float16)a.z; r[3] = (_Float16)a.w;
  r[4] = (_Float16)b.x; r[5] = (_Float16)b.y;
  r[6] = (_Float16)b.z; r[7] = (_Float16)b.w;
  return r;
}

__global__ __launch_bounds__(256) void local_attn_kernel(
    const float* __restrict__ q, const float* __restrict__ k,
    const float* __restrict__ v, float* __restrict__ out) {
  constexpr int PROW = 136;              // f16 elems per P row (272 B, 16B-aligned, odd 16B count)
  __shared__ _Float16 Plds[4][NQ * PROW];

  const int wave = threadIdx.x >> 6;
  const int lane = threadIdx.x & 63;
  const int lr = lane & 15;              // col / row-in-16 index
  const int lg = lane >> 4;              // 4 lane-groups

  const int g = blockIdx.x * 4 + wave;   // global trunk id, 0..8191
  const int h = g >> 9;                  // head
  const int tr = g & (TPH - 1);          // trunk within head
  const int q0 = tr * NQ;                // first query row of trunk

  const float* __restrict__ qh = q + (size_t)h * NSEQ * DHEAD;
  const float* __restrict__ kh = k + (size_t)h * NSEQ * DHEAD;
  const float* __restrict__ vh = v + (size_t)h * NSEQ * DHEAD;

  // ---------------- Q fragments (A operand), direct from global ----------
  // A-frag 16x16x32: lane holds A[row=lane&15][k=(lane>>4)*8 + j], j=0..7
  f16x8 aq[2][2];
  #pragma unroll
  for (int m = 0; m < 2; ++m)
    #pragma unroll
    for (int s = 0; s < 2; ++s)
      aq[m][s] = cvt8(qh + (size_t)(q0 + m * 16 + lr) * DHEAD + s * 32 + lg * 8);

  // ---------------- S = Q K^T  (32 x 128) --------------------------------
  // C layout: col = lane&15 (+16n), row = (lane>>4)*4 + reg (+16m)
  f32x4 sc[2][8];
  #pragma unroll
  for (int m = 0; m < 2; ++m)
    #pragma unroll
    for (int n = 0; n < 8; ++n)
      sc[m][n] = (f32x4){0.f, 0.f, 0.f, 0.f};

  #pragma unroll
  for (int n = 0; n < 8; ++n) {
    const int kb = q0 - PADL + n * 16 + lr;        // global key index of this col
    const int kc = min(max(kb, 0), NSEQ - 1);      // clamped for safe load
    #pragma unroll
    for (int s = 0; s < 2; ++s) {
      // B-frag: lane holds K^T[k=(lane>>4)*8+j][col] = K[col][d contiguous]
      f16x8 bk = cvt8(kh + (size_t)kc * DHEAD + s * 32 + lg * 8);
      sc[0][n] = __builtin_amdgcn_mfma_f32_16x16x32_f16(aq[0][s], bk, sc[0][n], 0, 0, 0);
      sc[1][n] = __builtin_amdgcn_mfma_f32_16x16x32_f16(aq[1][s], bk, sc[1][n], 0, 0, 0);
    }
    if ((unsigned)kb >= (unsigned)NSEQ) {          // mask invalid key columns
      #pragma unroll
      for (int m = 0; m < 2; ++m)
        #pragma unroll
        for (int r = 0; r < 4; ++r) sc[m][n][r] = -1e30f;
    }
  }

  // ---------------- softmax over 128 keys --------------------------------
  float mx[2][4], sm[2][4];
  #pragma unroll
  for (int m = 0; m < 2; ++m)
    #pragma unroll
    for (int r = 0; r < 4; ++r) {
      float t = -1e30f;
      #pragma unroll
      for (int n = 0; n < 8; ++n) t = fmaxf(t, sc[m][n][r]);
      #pragma unroll
      for (int off = 1; off < 16; off <<= 1) t = fmaxf(t, __shfl_xor(t, off));
      mx[m][r] = t;
    }
  #pragma unroll
  for (int m = 0; m < 2; ++m)
    #pragma unroll
    for (int r = 0; r < 4; ++r) {
      float s = 0.f;
      #pragma unroll
      for (int n = 0; n < 8; ++n) {
        float p = __expf(sc[m][n][r] - mx[m][r]);
        sc[m][n][r] = p;
        s += p;
      }
      #pragma unroll
      for (int off = 1; off < 16; off <<= 1) s += __shfl_xor(s, off);
      sm[m][r] = 1.f / s;
    }

  // ---------------- P -> LDS (re-layout for PV A-fragments) --------------
  _Float16* __restrict__ P = Plds[wave];
  #pragma unroll
  for (int m = 0; m < 2; ++m)
    #pragma unroll
    for (int n = 0; n < 8; ++n)
      #pragma unroll
      for (int r = 0; r < 4; ++r)
        P[(m * 16 + lg * 4 + r) * PROW + n * 16 + lr] =
            (_Float16)(sc[m][n][r] * sm[m][r]);

  // ---------------- O = P V  (32 x 64) -----------------------------------
  f32x4 oc[2][4];
  #pragma unroll
  for (int m = 0; m < 2; ++m)
    #pragma unroll
    for (int nt = 0; nt < 4; ++nt)
      oc[m][nt] = (f32x4){0.f, 0.f, 0.f, 0.f};

  #pragma unroll
  for (int ks = 0; ks < 4; ++ks) {
    // A-frags of P: lane reads P[row=lane&15(+16m)][ks*32 + (lane>>4)*8 ..+7]
    const f16x8 ap0 = *reinterpret_cast<const f16x8*>(&P[(lr) * PROW + ks * 32 + lg * 8]);
    const f16x8 ap1 = *reinterpret_cast<const f16x8*>(&P[(16 + lr) * PROW + ks * 32 + lg * 8]);
    const int key0 = q0 - PADL + ks * 32 + lg * 8;
    #pragma unroll
    for (int nt = 0; nt < 4; ++nt) {
      const int d = nt * 16 + lr;
      // B-frag of V: lane holds V[k=key0+j][col=d], j=0..7 (column reads,
      // but 16 consecutive lanes cover 64B contiguous -> coalesced)
      f16x8 bv;
      #pragma unroll
      for (int j = 0; j < 8; ++j) {
        const int kc = min(max(key0 + j, 0), NSEQ - 1);
        bv[j] = (_Float16)vh[(size_t)kc * DHEAD + d];
      }
      oc[0][nt] = __builtin_amdgcn_mfma_f32_16x16x32_f16(ap0, bv, oc[0][nt], 0, 0, 0);
      oc[1][nt] = __builtin_amdgcn_mfma_f32_16x16x32_f16(ap1, bv, oc[1][nt], 0, 0, 0);
    }
  }

  // ---------------- store O ----------------------------------------------
  float* __restrict__ oh = out + (size_t)h * NSEQ * DHEAD;
  #pragma unroll
  for (int m = 0; m < 2; ++m)
    #pragma unroll
    for (int nt = 0; nt < 4; ++nt)
      #pragma unroll
      for (int r = 0; r < 4; ++r)
        oh[(size_t)(q0 + m * 16 + lg * 4 + r) * DHEAD + nt * 16 + lr] = oc[m][nt][r];
}

extern "C" void kernel_launch(void* const* d_in, const int* in_sizes, int n_in,
                              void* d_out, int out_size, void* d_ws, size_t ws_size,
                              hipStream_t stream) {
  const float* q = (const float*)d_in[0];
  const float* k = (const float*)d_in[1];
  const float* v = (const float*)d_in[2];
  float* out = (float*)d_out;
  // 16 heads * 512 trunks = 8192 trunks; 4 waves (trunks) per 256-thread block
  dim3 grid(2048), block(256);
  hipLaunchKernelGGL(local_attn_kernel, grid, block, 0, stream, q, k, v, out);
}

// Round 2
// 63.620 us; speedup vs baseline: 1.3513x; 1.3513x over previous
//
#include <hip/hip_runtime.h>
#include <hip/hip_bf16.h>

// Local (trunked) attention, MI355X gfx950.
// B=1, H=16, N=16384, d=64 fp32; 32-query trunks x 128-key window, pad_left=48,
// no 1/sqrt(d) scaling. One wave per trunk, swapped-QK^T 32x32 MFMA structure:
// S^T = K Q^T so softmax is per-lane; P re-laid out in-register via
// cvt_pkrtz + permlane32_swap; V double-buffered in registers. Zero LDS.

typedef _Float16 f16x8 __attribute__((ext_vector_type(8)));
typedef float f32x16 __attribute__((ext_vector_type(16)));
typedef unsigned int u32;

#define NSEQ  16384
#define DHEAD 64
#define LOG2E 1.44269504088896340736f

// 8 consecutive f32 -> f16x8 (RNE scalar converts; optional scale)
__device__ __forceinline__ f16x8 cvt8(const float* __restrict__ p, float s) {
  const float4 a = *reinterpret_cast<const float4*>(p);
  const float4 b = *reinterpret_cast<const float4*>(p + 4);
  f16x8 r;
  r[0] = (_Float16)(a.x * s); r[1] = (_Float16)(a.y * s);
  r[2] = (_Float16)(a.z * s); r[3] = (_Float16)(a.w * s);
  r[4] = (_Float16)(b.x * s); r[5] = (_Float16)(b.y * s);
  r[6] = (_Float16)(b.z * s); r[7] = (_Float16)(b.w * s);
  return r;
}

// half-wave exchange: a' = {lo: a(own, hi'=0 halves), hi: partner's b}
//                     b' = {lo: partner's a, hi: b(own)}
__device__ __forceinline__ void plswap(u32& a, u32& b, int hi) {
#if __has_builtin(__builtin_amdgcn_permlane32_swap)
  typedef u32 u32x2 __attribute__((ext_vector_type(2)));
  u32x2 r = __builtin_amdgcn_permlane32_swap(a, b, false, false);
  a = r[0]; b = r[1];
#else
  u32 sa = (u32)__shfl_xor((int)a, 32);
  u32 sb = (u32)__shfl_xor((int)b, 32);
  u32 na = hi ? sb : a;
  u32 nb = hi ? b : sa;
  a = na; b = nb;
#endif
}

// one V chunk: 32 keys (two 16-key k-steps) x both 32-col d-tiles
__device__ __forceinline__ void load_vchunk(const float* __restrict__ vh, int base,
                                            int hi, int l31, float (&dst)[2][8][2]) {
  #pragma unroll
  for (int b = 0; b < 2; ++b)
    #pragma unroll
    for (int j = 0; j < 8; ++j) {
      int row = base + b * 16 + hi * 8 + j;
      row = min(max(row, 0), NSEQ - 1);
      const float* p = vh + (size_t)row * DHEAD + l31;
      dst[b][j][0] = p[0];
      dst[b][j][1] = p[32];
    }
}

__global__ __launch_bounds__(256) void local_attn_kernel(
    const float* __restrict__ q, const float* __restrict__ k,
    const float* __restrict__ v, float* __restrict__ out) {
  const int wave = threadIdx.x >> 6;
  const int lane = threadIdx.x & 63;
  const int l31 = lane & 31;
  const int hi  = lane >> 5;

  int bid = blockIdx.x;
  bid = (bid & 7) * 256 + (bid >> 3);        // XCD swizzle (2048 % 8 == 0)
  const int g   = bid * 4 + wave;            // trunk id 0..8191
  const int h   = g >> 9;
  const int q0  = (g & 511) << 5;            // first query row
  const int kb0 = q0 - 48;                   // window start (may be <0)

  const float* __restrict__ qh = q + (size_t)h * NSEQ * DHEAD;
  const float* __restrict__ kh = k + (size_t)h * NSEQ * DHEAD;
  const float* __restrict__ vh = v + (size_t)h * NSEQ * DHEAD;

  // ---------------- S^T = K Q^T  (128 keys x 32 queries) -----------------
  // D[m=key][n=q]: col = lane&31 = q, row = (r&3)+8*(r>>2)+4*hi (+32*kt)
  f32x16 sacc[4] = {};
  #pragma unroll
  for (int ks = 0; ks < 4; ++ks) {           // d in steps of 16
    // B-frag: Q^T[k=d][col=q]: lane holds Q[q0+l31][ks*16 + hi*8 + j] (log2e-scaled)
    const f16x8 qf = cvt8(qh + (size_t)(q0 + l31) * DHEAD + ks * 16 + hi * 8, LOG2E);
    #pragma unroll
    for (int kt = 0; kt < 4; ++kt) {         // key tiles of 32
      int kr = kb0 + kt * 32 + l31;
      kr = min(max(kr, 0), NSEQ - 1);
      const f16x8 kf = cvt8(kh + (size_t)kr * DHEAD + ks * 16 + hi * 8, 1.0f);
      sacc[kt] = __builtin_amdgcn_mfma_f32_32x32x16_f16(kf, qf, sacc[kt], 0, 0, 0);
    }
  }

  // ---------------- prefetch V chunk 0 (keys 0..31 of window) ------------
  float vr[2][2][8][2];                      // [buf][kstep][j][d-tile]
  load_vchunk(vh, kb0, hi, l31, vr[0]);

  // ---------------- mask invalid keys (only 4 trunks per head) -----------
  if (q0 < 48 || q0 > NSEQ - 80) {
    #pragma unroll
    for (int kt = 0; kt < 4; ++kt)
      #pragma unroll
      for (int r = 0; r < 16; ++r) {
        const int key = kb0 + kt * 32 + (r & 3) + 8 * (r >> 2) + 4 * hi;
        if ((unsigned)key >= (unsigned)NSEQ) sacc[kt][r] = -1e30f;
      }
  }

  // ---------------- per-lane softmax over 128 keys (base-2 domain) -------
  float mx = -1e30f;
  #pragma unroll
  for (int kt = 0; kt < 4; ++kt)
    #pragma unroll
    for (int r = 0; r < 16; ++r) mx = fmaxf(mx, sacc[kt][r]);
  mx = fmaxf(mx, __shfl_xor(mx, 32));
  float sum = 0.f;
  #pragma unroll
  for (int kt = 0; kt < 4; ++kt)
    #pragma unroll
    for (int r = 0; r < 16; ++r) {
      const float p = exp2f(sacc[kt][r] - mx);
      sacc[kt][r] = p;
      sum += p;
    }
  sum += __shfl_xor(sum, 32);
  const float inv = 1.0f / sum;

  // ---------------- P -> A-fragments in-register -------------------------
  // lane needs A[row=q=lane&31][k=key]; holds P[q][key=crow(r,hi)+32kt].
  // pack pairs, then permlane32_swap merges the two hi-halves' key sets.
  f16x8 pa[4][2];
  #pragma unroll
  for (int kt = 0; kt < 4; ++kt) {
    u32 pk[8];
    #pragma unroll
    for (int c = 0; c < 8; ++c) {
      auto h2 = __builtin_amdgcn_cvt_pkrtz(sacc[kt][2 * c] * inv,
                                           sacc[kt][2 * c + 1] * inv);
      pk[c] = __builtin_bit_cast(u32, h2);
    }
    plswap(pk[0], pk[2], hi); plswap(pk[1], pk[3], hi);
    plswap(pk[4], pk[6], hi); plswap(pk[5], pk[7], hi);
    union { f16x8 f; u32 u[4]; } f0, f1;
    f0.u[0] = pk[0]; f0.u[1] = pk[1]; f0.u[2] = pk[2]; f0.u[3] = pk[3];
    f1.u[0] = pk[4]; f1.u[1] = pk[5]; f1.u[2] = pk[6]; f1.u[3] = pk[7];
    pa[kt][0] = f0.f;
    pa[kt][1] = f1.f;
  }

  // ---------------- O = P V  (32 x 64), V double-buffered ----------------
  f32x16 oacc[2] = {};
  #pragma unroll
  for (int kt = 0; kt < 4; ++kt) {
    if (kt < 3) load_vchunk(vh, kb0 + (kt + 1) * 32, hi, l31, vr[(kt + 1) & 1]);
    #pragma unroll
    for (int b = 0; b < 2; ++b) {
      f16x8 bv0, bv1;
      #pragma unroll
      for (int j = 0; j < 8; ++j) {
        bv0[j] = (_Float16)vr[kt & 1][b][j][0];
        bv1[j] = (_Float16)vr[kt & 1][b][j][1];
      }
      oacc[0] = __builtin_amdgcn_mfma_f32_32x32x16_f16(pa[kt][b], bv0, oacc[0], 0, 0, 0);
      oacc[1] = __builtin_amdgcn_mfma_f32_32x32x16_f16(pa[kt][b], bv1, oacc[1], 0, 0, 0);
    }
  }

  // ---------------- store O ----------------------------------------------
  float* __restrict__ oh = out + (size_t)h * NSEQ * DHEAD;
  #pragma unroll
  for (int r = 0; r < 16; ++r) {
    const int row = q0 + (r & 3) + 8 * (r >> 2) + 4 * hi;
    float* po = oh + (size_t)row * DHEAD + l31;
    po[0]  = oacc[0][r];
    po[32] = oacc[1][r];
  }
}

extern "C" void kernel_launch(void* const* d_in, const int* in_sizes, int n_in,
                              void* d_out, int out_size, void* d_ws, size_t ws_size,
                              hipStream_t stream) {
  const float* q = (const float*)d_in[0];
  const float* k = (const float*)d_in[1];
  const float* v = (const float*)d_in[2];
  float* out = (float*)d_out;
  dim3 grid(2048), block(256);   // 8192 trunks, 4 waves (trunks) per block
  hipLaunchKernelGGL(local_attn_kernel, grid, block, 0, stream, q, k, v, out);
}

// Round 3
// 45.777 us; speedup vs baseline: 1.8779x; 1.3898x over previous
//
#include <hip/hip_runtime.h>
#include <hip/hip_bf16.h>

// Local (trunked) attention, MI355X gfx950.
// B=1, H=16, N=16384, d=64 fp32; 32-query trunks x 128-key window, pad_left=48.
// Block = 4 waves = 4 consecutive trunks of one head. K/V window union
// (224 rows) staged once per block into LDS as f16 (XOR-swizzled), then each
// wave computes its trunk with the swapped-QK^T 32x32 MFMA structure:
// S^T = K Q^T (softmax per-lane), P re-laid out in-register via
// cvt_pkrtz + permlane32_swap, V consumed from LDS.

typedef _Float16 f16x8 __attribute__((ext_vector_type(8)));
typedef float f32x16 __attribute__((ext_vector_type(16)));
typedef unsigned int u32;
typedef u32 u32x4 __attribute__((ext_vector_type(4)));

#define NSEQ   16384
#define DHEAD  64
#define LOG2E  1.44269504088896340736f
#define WROWS  224            // 128 queries + 96 window extension
#define RSTR   128            // LDS row stride in bytes (64 f16)
#define KBYTES (WROWS * RSTR) // 28672

__device__ __forceinline__ int swz(int r) {
  return ((r & 7) << 4) | ((r & 8) << 3);   // spread rows over 16 16B-slots
}

__device__ __forceinline__ u32 pk2(float a, float b) {
  auto h2 = __builtin_amdgcn_cvt_pkrtz(a, b);
  return __builtin_bit_cast(u32, h2);
}

// half-wave exchange of two packed regs (permlane32_swap)
__device__ __forceinline__ void plswap(u32& a, u32& b, int hi) {
#if __has_builtin(__builtin_amdgcn_permlane32_swap)
  typedef u32 u32x2 __attribute__((ext_vector_type(2)));
  u32x2 r = __builtin_amdgcn_permlane32_swap(a, b, false, false);
  a = r[0]; b = r[1];
#else
  u32 sa = (u32)__shfl_xor((int)a, 32);
  u32 sb = (u32)__shfl_xor((int)b, 32);
  u32 na = hi ? sb : a;
  u32 nb = hi ? b : sa;
  a = na; b = nb;
#endif
}

// Stage 224 rows x 64 cols f32 -> LDS f16 (swizzled). 256 threads, 7 iters.
__device__ __forceinline__ void stage224(const float* __restrict__ src, int grow0,
                                         char* __restrict__ dstc, int tid) {
  const int rsub = tid >> 3;          // 0..31
  const int c8   = (tid & 7) * 8;     // f32 col
  #pragma unroll
  for (int it = 0; it < 7; ++it) {
    const int r = it * 32 + rsub;
    const int g = min(max(grow0 + r, 0), NSEQ - 1);   // clamp; masked in S
    const float* p = src + (size_t)g * DHEAD + c8;
    const float4 a = *reinterpret_cast<const float4*>(p);
    const float4 b = *reinterpret_cast<const float4*>(p + 4);
    const u32x4 w = {pk2(a.x, a.y), pk2(a.z, a.w), pk2(b.x, b.y), pk2(b.z, b.w)};
    *reinterpret_cast<u32x4*>(dstc + ((r * RSTR + c8 * 2) ^ swz(r))) = w;
  }
}

__global__ __launch_bounds__(256, 2) void local_attn_kernel(
    const float* __restrict__ q, const float* __restrict__ k,
    const float* __restrict__ v, float* __restrict__ out) {
  __shared__ char smem[2 * KBYTES];   // 57,344 B: K then V
  char* const Kc = smem;
  char* const Vc = smem + KBYTES;

  const int tid  = threadIdx.x;
  const int wave = tid >> 6;
  const int lane = tid & 63;
  const int l31  = lane & 31;
  const int hi   = lane >> 5;

  int bid = blockIdx.x;
  bid = (bid & 7) * 256 + (bid >> 3);   // XCD swizzle (2048 % 8 == 0)
  const int h   = bid >> 7;             // head
  const int q0b = (bid & 127) << 7;     // block's first query row
  const int kg0 = q0b - 48;             // global row of LDS row 0
  const int q0  = q0b + wave * 32;      // this wave's trunk
  const int kvb = wave * 32;            // wave's local key base in LDS

  const float* __restrict__ qh = q + (size_t)h * NSEQ * DHEAD;
  const float* __restrict__ kh = k + (size_t)h * NSEQ * DHEAD;
  const float* __restrict__ vh = v + (size_t)h * NSEQ * DHEAD;

  // ---- Q raw loads issued before staging (latency hides under stage) ----
  float4 qr[4][2];
  #pragma unroll
  for (int ks = 0; ks < 4; ++ks) {
    const float* p = qh + (size_t)(q0 + l31) * DHEAD + ks * 16 + hi * 8;
    qr[ks][0] = *reinterpret_cast<const float4*>(p);
    qr[ks][1] = *reinterpret_cast<const float4*>(p + 4);
  }

  // ---- cooperative K/V staging (f32 -> f16, swizzled) -------------------
  stage224(kh, kg0, Kc, tid);
  stage224(vh, kg0, Vc, tid);
  __syncthreads();

  // ---- S^T = K Q^T  (128 keys x 32 queries) -----------------------------
  // D[m=key][n=q]: col = lane&31 = q, row = (r&3)+8*(r>>2)+4*hi (+32*kt)
  f32x16 sacc[4] = {};
  #pragma unroll
  for (int ks = 0; ks < 4; ++ks) {
    f16x8 qf;
    qf[0] = (_Float16)(qr[ks][0].x * LOG2E); qf[1] = (_Float16)(qr[ks][0].y * LOG2E);
    qf[2] = (_Float16)(qr[ks][0].z * LOG2E); qf[3] = (_Float16)(qr[ks][0].w * LOG2E);
    qf[4] = (_Float16)(qr[ks][1].x * LOG2E); qf[5] = (_Float16)(qr[ks][1].y * LOG2E);
    qf[6] = (_Float16)(qr[ks][1].z * LOG2E); qf[7] = (_Float16)(qr[ks][1].w * LOG2E);
    #pragma unroll
    for (int kt = 0; kt < 4; ++kt) {
      const int row = kvb + kt * 32 + l31;
      const f16x8 kf = *reinterpret_cast<const f16x8*>(
          Kc + ((row * RSTR + (ks * 16 + hi * 8) * 2) ^ swz(row)));
      sacc[kt] = __builtin_amdgcn_mfma_f32_32x32x16_f16(kf, qf, sacc[kt], 0, 0, 0);
    }
  }

  // ---- mask invalid keys (only edge trunks) -----------------------------
  if (q0 < 48 || q0 > NSEQ - 80) {
    #pragma unroll
    for (int kt = 0; kt < 4; ++kt)
      #pragma unroll
      for (int r = 0; r < 16; ++r) {
        const int key = (q0 - 48) + kt * 32 + (r & 3) + 8 * (r >> 2) + 4 * hi;
        if ((unsigned)key >= (unsigned)NSEQ) sacc[kt][r] = -1e30f;
      }
  }

  // ---- per-lane softmax over 128 keys (base-2 domain) -------------------
  float mx = -1e30f;
  #pragma unroll
  for (int kt = 0; kt < 4; ++kt)
    #pragma unroll
    for (int r = 0; r < 16; ++r) mx = fmaxf(mx, sacc[kt][r]);
  mx = fmaxf(mx, __shfl_xor(mx, 32));
  float sum = 0.f;
  #pragma unroll
  for (int kt = 0; kt < 4; ++kt)
    #pragma unroll
    for (int r = 0; r < 16; ++r) {
      const float p = exp2f(sacc[kt][r] - mx);
      sacc[kt][r] = p;
      sum += p;
    }
  sum += __shfl_xor(sum, 32);
  const float inv = 1.0f / sum;

  // ---- P -> A-fragments fully in-register -------------------------------
  f16x8 pa[4][2];
  #pragma unroll
  for (int kt = 0; kt < 4; ++kt) {
    u32 pk[8];
    #pragma unroll
    for (int c = 0; c < 8; ++c)
      pk[c] = pk2(sacc[kt][2 * c] * inv, sacc[kt][2 * c + 1] * inv);
    plswap(pk[0], pk[2], hi); plswap(pk[1], pk[3], hi);
    plswap(pk[4], pk[6], hi); plswap(pk[5], pk[7], hi);
    union { f16x8 f; u32 u[4]; } f0, f1;
    f0.u[0] = pk[0]; f0.u[1] = pk[1]; f0.u[2] = pk[2]; f0.u[3] = pk[3];
    f1.u[0] = pk[4]; f1.u[1] = pk[5]; f1.u[2] = pk[6]; f1.u[3] = pk[7];
    pa[kt][0] = f0.f;
    pa[kt][1] = f1.f;
  }

  // ---- O = P V  (32 x 64), V from LDS -----------------------------------
  f32x16 oacc[2] = {};
  #pragma unroll
  for (int kt = 0; kt < 4; ++kt) {
    #pragma unroll
    for (int b = 0; b < 2; ++b) {
      const int rbase = kvb + kt * 32 + b * 16 + hi * 8;
      f16x8 bv0, bv1;
      #pragma unroll
      for (int j = 0; j < 8; ++j) {
        const int row = rbase + j;           // row&7 == j, row&8 == 8*hi
        const int a0 = (row * RSTR + l31 * 2) ^ swz(row);
        const int a1 = (row * RSTR + l31 * 2 + 64) ^ swz(row);
        bv0[j] = *reinterpret_cast<const _Float16*>(Vc + a0);
        bv1[j] = *reinterpret_cast<const _Float16*>(Vc + a1);
      }
      oacc[0] = __builtin_amdgcn_mfma_f32_32x32x16_f16(pa[kt][b], bv0, oacc[0], 0, 0, 0);
      oacc[1] = __builtin_amdgcn_mfma_f32_32x32x16_f16(pa[kt][b], bv1, oacc[1], 0, 0, 0);
    }
  }

  // ---- store O ----------------------------------------------------------
  float* __restrict__ oh = out + (size_t)h * NSEQ * DHEAD;
  #pragma unroll
  for (int r = 0; r < 16; ++r) {
    const int row = q0 + (r & 3) + 8 * (r >> 2) + 4 * hi;
    float* po = oh + (size_t)row * DHEAD + l31;
    po[0]  = oacc[0][r];
    po[32] = oacc[1][r];
  }
}

extern "C" void kernel_launch(void* const* d_in, const int* in_sizes, int n_in,
                              void* d_out, int out_size, void* d_ws, size_t ws_size,
                              hipStream_t stream) {
  const float* q = (const float*)d_in[0];
  const float* k = (const float*)d_in[1];
  const float* v = (const float*)d_in[2];
  float* out = (float*)d_out;
  dim3 grid(2048), block(256);   // block = 4 consecutive trunks of one head
  hipLaunchKernelGGL(local_attn_kernel, grid, block, 0, stream, q, k, v, out);
}